// Round 1
// baseline (360.315 us; speedup 1.0000x reference)
//
#include <hip/hip_runtime.h>

#define NDIM 8192
#define ROWS_PER_BLOCK 4
#define BLOCK 256

__global__ __launch_bounds__(BLOCK) void stress_sum_kernel(
    const float* __restrict__ pos,
    const float* __restrict__ dist,
    float* __restrict__ out)
{
    const int row0 = blockIdx.x * ROWS_PER_BLOCK;

    // pos[i] for the block's rows (broadcast via scalar cache)
    float pix[ROWS_PER_BLOCK], piy[ROWS_PER_BLOCK];
#pragma unroll
    for (int r = 0; r < ROWS_PER_BLOCK; ++r) {
        pix[r] = pos[2 * (row0 + r)];
        piy[r] = pos[2 * (row0 + r) + 1];
    }

    float acc = 0.0f;

    // j sweep: each thread takes 4 consecutive columns per iteration
    for (int jb = threadIdx.x * 4; jb < NDIM; jb += BLOCK * 4) {
        // pos[j..j+3] as two float4 (32B-aligned since jb % 4 == 0)
        const float4 p01 = *(const float4*)(pos + 2 * jb);
        const float4 p23 = *(const float4*)(pos + 2 * jb + 4);
        const float pjx[4] = {p01.x, p01.z, p23.x, p23.z};
        const float pjy[4] = {p01.y, p01.w, p23.y, p23.w};

#pragma unroll
        for (int r = 0; r < ROWS_PER_BLOCK; ++r) {
            const float4 d4 =
                *(const float4*)(dist + (size_t)(row0 + r) * NDIM + jb);
            const float dv[4] = {d4.x, d4.y, d4.z, d4.w};
#pragma unroll
            for (int k = 0; k < 4; ++k) {
                const float dx = pjx[k] - pix[r];
                const float dy = pjy[k] - piy[r];
                const float sq = dx * dx + dy * dy;
                const float pred = sqrtf(sq);      // sqrt(0)=0 matches guard
                const float d = dv[k];
                // dist==0 branch of the reference contributes dist (=0)
                const float rcp = __builtin_amdgcn_rcpf(d);
                const float t = pred * rcp - 1.0f; // (pred-d)/d
                acc += (d != 0.0f) ? t * t : 0.0f;
            }
        }
    }

    // wave64 shuffle reduce
#pragma unroll
    for (int off = 32; off > 0; off >>= 1)
        acc += __shfl_down(acc, off, 64);

    __shared__ float wave_sums[BLOCK / 64];
    const int lane = threadIdx.x & 63;
    const int wave = threadIdx.x >> 6;
    if (lane == 0) wave_sums[wave] = acc;
    __syncthreads();

    if (threadIdx.x == 0) {
        float s = 0.0f;
#pragma unroll
        for (int w = 0; w < BLOCK / 64; ++w) s += wave_sums[w];
        atomicAdd(out, s);
    }
}

extern "C" void kernel_launch(void* const* d_in, const int* in_sizes, int n_in,
                              void* d_out, int out_size, void* d_ws, size_t ws_size,
                              hipStream_t stream)
{
    const float* pos  = (const float*)d_in[0];
    const float* dist = (const float*)d_in[1];
    float* out = (float*)d_out;

    // d_out is poisoned 0xAA before every launch — zero it (capture-safe)
    hipMemsetAsync(out, 0, sizeof(float) * out_size, stream);

    const int grid = NDIM / ROWS_PER_BLOCK; // 2048 blocks
    stress_sum_kernel<<<grid, BLOCK, 0, stream>>>(pos, dist, out);
}

// Round 2
// 352.702 us; speedup vs baseline: 1.0216x; 1.0216x over previous
//
#include <hip/hip_runtime.h>

#define NDIM 8192
#define ROWS_PER_BLOCK 4
#define BLOCK 256
#define GRID (NDIM / ROWS_PER_BLOCK)   // 2048 blocks
#define COLS_PER_THREAD 8              // 2 x float4 per row

__global__ __launch_bounds__(BLOCK) void stress_partial_kernel(
    const float* __restrict__ pos,
    const float* __restrict__ dist,
    float* __restrict__ partials)
{
    const int row0 = blockIdx.x * ROWS_PER_BLOCK;

    float pix[ROWS_PER_BLOCK], piy[ROWS_PER_BLOCK];
#pragma unroll
    for (int r = 0; r < ROWS_PER_BLOCK; ++r) {
        pix[r] = pos[2 * (row0 + r)];
        piy[r] = pos[2 * (row0 + r) + 1];
    }

    float acc = 0.0f;

    // each thread handles 8 consecutive columns; stride BLOCK*8 = 2048
    for (int jb = threadIdx.x * COLS_PER_THREAD; jb < NDIM; jb += BLOCK * COLS_PER_THREAD) {
        // pos[j..j+7]: four float4 (16B-aligned, jb%8==0 -> 2*jb%16==0)
        float pjx[COLS_PER_THREAD], pjy[COLS_PER_THREAD];
#pragma unroll
        for (int q = 0; q < 4; ++q) {
            const float4 p = *(const float4*)(pos + 2 * jb + 4 * q);
            pjx[2 * q]     = p.x;  pjy[2 * q]     = p.y;
            pjx[2 * q + 1] = p.z;  pjy[2 * q + 1] = p.w;
        }

#pragma unroll
        for (int r = 0; r < ROWS_PER_BLOCK; ++r) {
            const float* drow = dist + (size_t)(row0 + r) * NDIM + jb;
            const float4 d0 = *(const float4*)(drow);
            const float4 d1 = *(const float4*)(drow + 4);
            const float dv[COLS_PER_THREAD] = {d0.x, d0.y, d0.z, d0.w,
                                               d1.x, d1.y, d1.z, d1.w};
#pragma unroll
            for (int k = 0; k < COLS_PER_THREAD; ++k) {
                const float dx = pjx[k] - pix[r];
                const float dy = pjy[k] - piy[r];
                const float sq = dx * dx + dy * dy;
                const float pred = sqrtf(sq);            // sqrt(0)=0 matches guard
                const float d = dv[k];
                const float rcp = __builtin_amdgcn_rcpf(d);
                const float t = pred * rcp - 1.0f;       // (pred-d)/d
                acc += (d != 0.0f) ? t * t : 0.0f;       // dist==0 term contributes 0
            }
        }
    }

    // wave64 shuffle reduce
#pragma unroll
    for (int off = 32; off > 0; off >>= 1)
        acc += __shfl_down(acc, off, 64);

    __shared__ float wave_sums[BLOCK / 64];
    const int lane = threadIdx.x & 63;
    const int wave = threadIdx.x >> 6;
    if (lane == 0) wave_sums[wave] = acc;
    __syncthreads();

    if (threadIdx.x == 0) {
        float s = 0.0f;
#pragma unroll
        for (int w = 0; w < BLOCK / 64; ++w) s += wave_sums[w];
        partials[blockIdx.x] = s;   // overwrite: no zero-init needed
    }
}

__global__ __launch_bounds__(BLOCK) void reduce_final_kernel(
    const float* __restrict__ partials,
    float* __restrict__ out)
{
    float acc = 0.0f;
#pragma unroll
    for (int i = 0; i < GRID / BLOCK; ++i)          // 2048/256 = 8 per thread
        acc += partials[threadIdx.x + i * BLOCK];

#pragma unroll
    for (int off = 32; off > 0; off >>= 1)
        acc += __shfl_down(acc, off, 64);

    __shared__ float wave_sums[BLOCK / 64];
    const int lane = threadIdx.x & 63;
    const int wave = threadIdx.x >> 6;
    if (lane == 0) wave_sums[wave] = acc;
    __syncthreads();

    if (threadIdx.x == 0) {
        float s = 0.0f;
#pragma unroll
        for (int w = 0; w < BLOCK / 64; ++w) s += wave_sums[w];
        out[0] = s;                  // direct write: no memset node needed
    }
}

extern "C" void kernel_launch(void* const* d_in, const int* in_sizes, int n_in,
                              void* d_out, int out_size, void* d_ws, size_t ws_size,
                              hipStream_t stream)
{
    const float* pos  = (const float*)d_in[0];
    const float* dist = (const float*)d_in[1];
    float* out = (float*)d_out;
    float* partials = (float*)d_ws;

    stress_partial_kernel<<<GRID, BLOCK, 0, stream>>>(pos, dist, partials);
    reduce_final_kernel<<<1, BLOCK, 0, stream>>>(partials, out);
}